// Round 3
// baseline (562.628 us; speedup 1.0000x reference)
//
#include <hip/hip_runtime.h>

#define N_PIX 50176
#define W_IMG 224
#define NT2 49           // 16-row tiles per block column; 64 block-columns
#define ROWS 16

typedef __attribute__((ext_vector_type(8))) short s8v;   // 8 bf16
typedef __attribute__((ext_vector_type(4))) float f4v;
typedef __attribute__((ext_vector_type(2))) float f2v;

__device__ __forceinline__ unsigned short f2bf(float f) {
    __bf16 h = (__bf16)f;
    return __builtin_bit_cast(unsigned short, h);
}

#define SWZ(r, cb) (((r) << 8) + ((cb) ^ (((r) & 15) << 4)))

// ---------------------------------------------------------------------------
// K0: Wk[col][k] (bf16, [128][192]): k<128 -> (w_obs2 @ w_ol1_top)^T
//                                    k>=128 -> w_ol1_bot^T  (em_loc extension)
//     wol2t[o][k]  = w_ol2^T  (bf16, [64][128])
//     wloc2t[o][k] = w_loc2^T (bf16, [64][128])
//     bias_c[h2]   = b_ol1[h2] + b_obs2 @ w_ol1_top
// ---------------------------------------------------------------------------
__global__ void k0_weights(const float* __restrict__ w_obs2, const float* __restrict__ b_obs2,
                           const float* __restrict__ w_ol1, const float* __restrict__ b_ol1,
                           const float* __restrict__ w_ol2, const float* __restrict__ w_loc2,
                           unsigned short* __restrict__ Wk,
                           unsigned short* __restrict__ wol2t,
                           unsigned short* __restrict__ wloc2t,
                           float* __restrict__ bias_c) {
    int bid = blockIdx.x, t = threadIdx.x;
    if (bid < 64) {                       // 128x128 folded obs path
        int lin = bid * 256 + t;
        int n = lin >> 7, k = lin & 127;
        float s = 0.f;
        #pragma unroll
        for (int e = 0; e < 64; ++e) s = fmaf(w_obs2[k * 64 + e], w_ol1[e * 128 + n], s);
        Wk[n * 192 + k] = f2bf(s);
    } else if (bid < 96) {                // 128x64 loc extension
        int lin = (bid - 64) * 256 + t;
        int n = lin >> 6, k = lin & 63;
        Wk[n * 192 + 128 + k] = f2bf(w_ol1[(64 + k) * 128 + n]);
    } else if (bid < 128) {               // w_ol2 transpose
        int lin = (bid - 96) * 256 + t;
        int n = lin >> 7, k = lin & 127;
        wol2t[n * 128 + k] = f2bf(w_ol2[k * 64 + n]);
    } else if (bid < 160) {               // w_loc2 transpose
        int lin = (bid - 128) * 256 + t;
        int n = lin >> 7, k = lin & 127;
        wloc2t[n * 128 + k] = f2bf(w_loc2[k * 64 + n]);
    } else {
        if (t < 128) {
            float s = b_ol1[t];
            #pragma unroll
            for (int e = 0; e < 64; ++e) s = fmaf(b_obs2[e], w_ol1[e * 128 + t], s);
            bias_c[t] = s;
        }
    }
}

// ---------------------------------------------------------------------------
// K1: em_loc via MFMA. Block = 64 pixels, 256 threads (4 waves).
//   S1: hv = relu(y*w1y + x*w1x + b1) -> LDS bf16 (swz)
//   S2: em_loc = hv @ w_loc2 + b_loc2 via 16 MFMAs/wave -> global bf16 [N][64]
// ---------------------------------------------------------------------------
__global__ __launch_bounds__(256) void k1_loc(
        const float* __restrict__ w_loc1, const float* __restrict__ b_loc1,
        const unsigned short* __restrict__ wloc2t, const float* __restrict__ b_loc2,
        unsigned short* __restrict__ emloc) {
    __shared__ char hbuf[64 * 256];
    typedef __attribute__((ext_vector_type(4))) unsigned int u4v;

    const int t = threadIdx.x;
    const int n0 = blockIdx.x * 64;
    const int row = t >> 2, h0 = (t & 3) * 32;
    {
        int n = n0 + row;
        int iy = n / W_IMG, ix = n % W_IMG;
        float y = -10.f + (20.f / 223.f) * (float)iy;
        float x = -10.f + (20.f / 223.f) * (float)ix;
        #pragma unroll
        for (int q4 = 0; q4 < 4; ++q4) {
            int hb = h0 + q4 * 8;
            u4v pk;
            #pragma unroll
            for (int jj = 0; jj < 2; ++jj) {
                f4v wy = *(const f4v*)(w_loc1 + hb + jj * 4);
                f4v wx = *(const f4v*)(w_loc1 + 128 + hb + jj * 4);
                f4v bb = *(const f4v*)(b_loc1 + hb + jj * 4);
                #pragma unroll
                for (int j2 = 0; j2 < 2; ++j2) {
                    float v0 = fmaxf(fmaf(y, wy[j2 * 2], fmaf(x, wx[j2 * 2], bb[j2 * 2])), 0.f);
                    float v1 = fmaxf(fmaf(y, wy[j2 * 2 + 1], fmaf(x, wx[j2 * 2 + 1], bb[j2 * 2 + 1])), 0.f);
                    pk[jj * 2 + j2] = (unsigned int)f2bf(v0) | ((unsigned int)f2bf(v1) << 16);
                }
            }
            *(u4v*)(hbuf + SWZ(row, hb * 2)) = pk;
        }
    }
    __syncthreads();
    {
        const int w = t >> 6, l = t & 63;
        const int l15 = l & 15, lg = l >> 4;
        s8v a[4];
        #pragma unroll
        for (int ks = 0; ks < 4; ++ks)
            a[ks] = *(const s8v*)(hbuf + SWZ(w * 16 + l15, ks * 64 + lg * 16));
        #pragma unroll
        for (int nt = 0; nt < 4; ++nt) {
            f4v acc = {0.f, 0.f, 0.f, 0.f};
            #pragma unroll
            for (int ks = 0; ks < 4; ++ks) {
                s8v bfr = *(const s8v*)(wloc2t + (nt * 16 + l15) * 128 + ks * 32 + lg * 8);
                acc = __builtin_amdgcn_mfma_f32_16x16x32_bf16(a[ks], bfr, acc, 0, 0, 0);
            }
            float bb = b_loc2[nt * 16 + l15];
            #pragma unroll
            for (int r = 0; r < 4; ++r) {
                int n = n0 + w * 16 + lg * 4 + r;
                emloc[(size_t)n * 64 + nt * 16 + l15] = f2bf(acc[r] + bb);
            }
        }
    }
}

// ---------------------------------------------------------------------------
// K2: 3-stage pipeline, 1 barrier/iter, 16-row tiles, 256-thread blocks.
//   S1 (VALU, pk-f32): hidden_obs(tile i) -> bufA[i&1]
//   S3 (MFMA): relu(bufA@Wk_ext + bias) (tile i-1) -> bufB[(i-1)&1], K=192
//   S4 (MFMA): softplus(bufB@w_ol2 + b_ol2) (tile i-2) -> spacc
// 4 waves: cq = w owns GEMM1 cols [cq*32,+32) and GEMM2 o-cols [cq*16,+16).
// ---------------------------------------------------------------------------
__global__ __launch_bounds__(256, 4) void k2_main(
        const float* __restrict__ images,
        const float* __restrict__ w_obs1, const float* __restrict__ b_obs1,
        const unsigned short* __restrict__ Wk, const float* __restrict__ biasc,
        const unsigned short* __restrict__ wol2t, const float* __restrict__ b_ol2,
        const unsigned short* __restrict__ emloc,
        float* __restrict__ part)          // [32][64][64]
{
    __shared__ char bufA[2][ROWS * 256];
    __shared__ char bufB[2][ROWS * 256];
    __shared__ float red[4][16];

    const int t = threadIdx.x;
    const int w = t >> 6, l = t & 63;
    const int l15 = l & 15, lg = l >> 4;
    const int cq = w;
    const int bx = blockIdx.x, b = blockIdx.y;
    const int base = bx * (NT2 * ROWS);
    const size_t imgb = (size_t)b * 3 * N_PIX;

    // S1 statics: thread owns rows {2q, 2q+1} x h [h0, h0+4)
    const int q = t >> 5;
    const int h0 = (t & 31) * 4;
    const f4v s1w0 = *(const f4v*)(w_obs1 + h0);
    const f4v s1w1 = *(const f4v*)(w_obs1 + 128 + h0);
    const f4v s1w2 = *(const f4v*)(w_obs1 + 256 + h0);
    const f4v s1b  = *(const f4v*)(b_obs1 + h0);

    // GEMM1 B fragments (persistent): 2 n-tiles x 6 k-steps
    s8v bw[2][6];
    #pragma unroll
    for (int nt = 0; nt < 2; ++nt) {
        int col = cq * 32 + nt * 16 + l15;
        #pragma unroll
        for (int ks = 0; ks < 6; ++ks)
            bw[nt][ks] = *(const s8v*)(Wk + col * 192 + ks * 32 + lg * 8);
    }
    // GEMM2 B fragments (persistent)
    s8v w2f[4];
    {
        int o = cq * 16 + l15;
        #pragma unroll
        for (int ks = 0; ks < 4; ++ks)
            w2f[ks] = *(const s8v*)(wol2t + o * 128 + ks * 32 + lg * 8);
    }
    const float bias30 = biasc[cq * 32 + l15];
    const float bias31 = biasc[cq * 32 + 16 + l15];
    const float bias4  = b_ol2[cq * 16 + l15];

    float spacc = 0.f;

    for (int i = 0; i <= NT2 + 1; ++i) {
        // ---- S1: hidden_obs(tile i) -> bufA[i&1], packed f32 over row pairs
        if (i < NT2) {
            int n = base + i * ROWS + 2 * q;
            const float* ip = images + imgb + n;
            f2v xa = *(const f2v*)(ip);
            f2v xb = *(const f2v*)(ip + N_PIX);
            f2v xc = *(const f2v*)(ip + 2 * N_PIX);
            f2v hv[4];
            #pragma unroll
            for (int j = 0; j < 4; ++j) {
                f2v v = xa * s1w0[j] + xb * s1w1[j] + xc * s1w2[j] + s1b[j];
                f2v z = {0.f, 0.f};
                hv[j] = __builtin_elementwise_max(v, z);
            }
            char* bA = bufA[i & 1];
            unsigned int p00 = (unsigned int)f2bf(hv[0].x) | ((unsigned int)f2bf(hv[1].x) << 16);
            unsigned int p01 = (unsigned int)f2bf(hv[2].x) | ((unsigned int)f2bf(hv[3].x) << 16);
            unsigned int p10 = (unsigned int)f2bf(hv[0].y) | ((unsigned int)f2bf(hv[1].y) << 16);
            unsigned int p11 = (unsigned int)f2bf(hv[2].y) | ((unsigned int)f2bf(hv[3].y) << 16);
            *(uint2*)(bA + SWZ(2 * q, h0 * 2)) = make_uint2(p00, p01);
            *(uint2*)(bA + SWZ(2 * q + 1, h0 * 2)) = make_uint2(p10, p11);
        }
        // ---- S3: relu(GEMM1 ext-K) (tile i-1) -> bufB[(i-1)&1]
        if (i >= 1 && i <= NT2) {
            const char* bA = bufA[(i - 1) & 1];
            f4v acc0 = {0.f, 0.f, 0.f, 0.f}, acc1 = {0.f, 0.f, 0.f, 0.f};
            s8v a[4];
            #pragma unroll
            for (int ks = 0; ks < 4; ++ks)
                a[ks] = *(const s8v*)(bA + SWZ(l15, ks * 64 + lg * 16));
            int n = base + (i - 1) * ROWS + l15;
            const unsigned short* ep = emloc + (size_t)n * 64 + lg * 8;
            s8v a4 = *(const s8v*)(ep);
            s8v a5 = *(const s8v*)(ep + 32);
            __builtin_amdgcn_s_setprio(1);
            #pragma unroll
            for (int ks = 0; ks < 4; ++ks) {
                acc0 = __builtin_amdgcn_mfma_f32_16x16x32_bf16(a[ks], bw[0][ks], acc0, 0, 0, 0);
                acc1 = __builtin_amdgcn_mfma_f32_16x16x32_bf16(a[ks], bw[1][ks], acc1, 0, 0, 0);
            }
            acc0 = __builtin_amdgcn_mfma_f32_16x16x32_bf16(a4, bw[0][4], acc0, 0, 0, 0);
            acc1 = __builtin_amdgcn_mfma_f32_16x16x32_bf16(a4, bw[1][4], acc1, 0, 0, 0);
            acc0 = __builtin_amdgcn_mfma_f32_16x16x32_bf16(a5, bw[0][5], acc0, 0, 0, 0);
            acc1 = __builtin_amdgcn_mfma_f32_16x16x32_bf16(a5, bw[1][5], acc1, 0, 0, 0);
            __builtin_amdgcn_s_setprio(0);
            char* bB = bufB[(i - 1) & 1];
            #pragma unroll
            for (int r = 0; r < 4; ++r) {
                int row = lg * 4 + r;
                float v0 = fmaxf(acc0[r] + bias30, 0.f);
                float v1 = fmaxf(acc1[r] + bias31, 0.f);
                int cb = (cq * 32 + l15) * 2 ^ ((row & 15) << 4);
                *(unsigned short*)(bB + (row << 8) + cb) = f2bf(v0);
                *(unsigned short*)(bB + (row << 8) + (cb ^ 32)) = f2bf(v1);
            }
        }
        // ---- S4: softplus(GEMM2) (tile i-2) -> spacc
        if (i >= 2) {
            const char* bB = bufB[i & 1];
            f4v acc = {0.f, 0.f, 0.f, 0.f};
            s8v a[4];
            #pragma unroll
            for (int ks = 0; ks < 4; ++ks)
                a[ks] = *(const s8v*)(bB + SWZ(l15, ks * 64 + lg * 16));
            __builtin_amdgcn_s_setprio(1);
            #pragma unroll
            for (int ks = 0; ks < 4; ++ks)
                acc = __builtin_amdgcn_mfma_f32_16x16x32_bf16(a[ks], w2f[ks], acc, 0, 0, 0);
            __builtin_amdgcn_s_setprio(0);
            #pragma unroll
            for (int r = 0; r < 4; ++r) {
                float xv = acc[r] + bias4;
                spacc += fmaxf(xv, 0.f) + __logf(1.f + __expf(-fabsf(xv)));
            }
        }
        __syncthreads();
    }

    // column reduction: lane's o = cq*16 + l15; sum over lg groups
    spacc += __shfl_xor(spacc, 16, 64);
    spacc += __shfl_xor(spacc, 32, 64);
    if (l < 16) red[w][l] = spacc;
    __syncthreads();
    if (t < 64) part[((size_t)b * 64 + bx) * 64 + t] = red[t >> 4][t & 15];
}

// ---------------------------------------------------------------------------
// K3: reduce partials + cls MLP (fp32), one block per image
// ---------------------------------------------------------------------------
__global__ __launch_bounds__(128) void k3_cls(
        const float* __restrict__ part,
        const float* __restrict__ w_cls1, const float* __restrict__ b_cls1,
        const float* __restrict__ w_cls2, const float* __restrict__ b_cls2,
        float* __restrict__ out) {
    __shared__ float es[64];
    __shared__ float hid[128];
    const int b = blockIdx.x, t = threadIdx.x;
    if (t < 64) {
        float s = 0.f;
        #pragma unroll 8
        for (int x = 0; x < 64; ++x) s += part[((size_t)b * 64 + x) * 64 + t];
        es[t] = s;
    }
    __syncthreads();
    {
        float s = b_cls1[t];
        #pragma unroll
        for (int e = 0; e < 64; ++e) s = fmaf(es[e], w_cls1[e * 128 + t], s);
        hid[t] = fmaxf(s, 0.f);
    }
    __syncthreads();
    if (t < 10) {
        float s = b_cls2[t];
        #pragma unroll
        for (int h = 0; h < 128; ++h) s = fmaf(hid[h], w_cls2[h * 10 + t], s);
        out[b * 10 + t] = s;
    }
}

extern "C" void kernel_launch(void* const* d_in, const int* in_sizes, int n_in,
                              void* d_out, int out_size, void* d_ws, size_t ws_size,
                              hipStream_t stream) {
    (void)in_sizes; (void)n_in; (void)out_size; (void)ws_size;
    const float* images = (const float*)d_in[0];
    const float* w_obs1 = (const float*)d_in[1];
    const float* b_obs1 = (const float*)d_in[2];
    const float* w_obs2 = (const float*)d_in[3];
    const float* b_obs2 = (const float*)d_in[4];
    const float* w_loc1 = (const float*)d_in[5];
    const float* b_loc1 = (const float*)d_in[6];
    const float* w_loc2 = (const float*)d_in[7];
    const float* b_loc2 = (const float*)d_in[8];
    const float* w_ol1  = (const float*)d_in[9];
    const float* b_ol1  = (const float*)d_in[10];
    const float* w_ol2  = (const float*)d_in[11];
    const float* b_ol2  = (const float*)d_in[12];
    const float* w_cls1 = (const float*)d_in[13];
    const float* b_cls1 = (const float*)d_in[14];
    const float* w_cls2 = (const float*)d_in[15];
    const float* b_cls2 = (const float*)d_in[16];

    char* ws = (char*)d_ws;
    float* part           = (float*)(ws);                   // 32*64*64*4  = 524288
    float* biasc          = (float*)(ws + 524288);          // 128*4       = 512
    unsigned short* Wk    = (unsigned short*)(ws + 524800); // 128*192*2   = 49152
    unsigned short* wol2t = (unsigned short*)(ws + 573952); // 64*128*2    = 16384
    unsigned short* wloc2t= (unsigned short*)(ws + 590336); // 64*128*2    = 16384
    unsigned short* emloc = (unsigned short*)(ws + 606720); // 50176*64*2  = 6422528

    hipLaunchKernelGGL(k0_weights, dim3(161), dim3(256), 0, stream,
                       w_obs2, b_obs2, w_ol1, b_ol1, w_ol2, w_loc2, Wk, wol2t, wloc2t, biasc);
    hipLaunchKernelGGL(k1_loc, dim3(784), dim3(256), 0, stream,
                       w_loc1, b_loc1, wloc2t, b_loc2, emloc);
    hipLaunchKernelGGL(k2_main, dim3(64, 32), dim3(256), 0, stream,
                       images, w_obs1, b_obs1, Wk, biasc, wol2t, b_ol2, emloc, part);
    hipLaunchKernelGGL(k3_cls, dim3(32), dim3(128), 0, stream,
                       part, w_cls1, b_cls1, w_cls2, b_cls2, (float*)d_out);
}